// Round 11
// baseline (105.131 us; speedup 1.0000x reference)
//
#include <hip/hip_runtime.h>

// LatencyEncoder R10 = R7 (79.7us best) with ONE change: K2 prefetches all 50
// latency bytes up front (fully-unrolled two-pass body), removing the
// dependent global_load_ubyte from the steady-state store loop.
//  - K1: byte-identical to R7 (scalar f64 chain, 1024 blocks). R9 showed K1
//    cost is negligible; f64 chain matches numpy ref bit-exactly (absmax 0.0
//    in every passing round).
//  - K2 fast path (exact shape 2048*256*50 == n4): pass 1 issues 50 ubyte
//    loads (static unroll -> registers, <=63 outstanding); pass 2 is a pure
//    select+store stream. Same grid/order as R7 (32 waves/CU, grid-stride).
//  - General-shape fallback = R7's K2 loop; ws fallback = R0 fused kernel.

#define T 100
#define K2_GRID 2048
#define K2_STRIDE (K2_GRID * 256)   // 524,288
#define K2_ITERS 50                 // 26,214,400 / 524,288

typedef float vf4 __attribute__((ext_vector_type(4)));

__device__ __forceinline__ int pair_latency_f64(float xv, float nv) {
  double xn = (double)xv + (double)nv * 0.01;
  double s = 1.0 / (1.0 + exp(-xn));
  int li = (int)rint((1.0 - s) * 99.0);
  li = li < 0 ? 0 : (li > 99 ? 99 : li);
  return (s > 0.5) ? li : 255;  // 255: no spike
}

__global__ __launch_bounds__(256) void lat_kernel(
    const float* __restrict__ x, const float* __restrict__ noise,
    unsigned char* __restrict__ lat, int npairs) {
  const int stride = gridDim.x * 256;
  for (int p = blockIdx.x * 256 + threadIdx.x; p < npairs; p += stride)
    lat[p] = (unsigned char)pair_latency_f64(x[p], noise[p]);
}

__device__ __forceinline__ vf4 onehot4(int L, int pos) {
  vf4 v;
  v.x = (L == pos + 0) ? 1.0f : 0.0f;
  v.y = (L == pos + 1) ? 1.0f : 0.0f;
  v.z = (L == pos + 2) ? 1.0f : 0.0f;
  v.w = (L == pos + 3) ? 1.0f : 0.0f;
  return v;
}

// K2 fast path: all lat loads batched up front; store loop has no VMEM reads.
__global__ __launch_bounds__(256) void onehot_stream_prefetch(
    const unsigned char* __restrict__ lat, vf4* __restrict__ o4) {
  const int i0 = blockIdx.x * 256 + threadIdx.x;
  unsigned char Lv[K2_ITERS];  // static-indexed via full unroll -> registers
#pragma unroll
  for (int k = 0; k < K2_ITERS; ++k) {
    const int i = i0 + k * K2_STRIDE;
    Lv[k] = lat[i / 25];
  }
#pragma unroll
  for (int k = 0; k < K2_ITERS; ++k) {
    const int i = i0 + k * K2_STRIDE;
    const int pair = i / 25;
    const int pos = (i - pair * 25) * 4;
    o4[i] = onehot4((int)Lv[k], pos);
  }
}

// K2 general shape (R7's exact loop).
__global__ __launch_bounds__(256) void onehot_stream_kernel(
    const unsigned char* __restrict__ lat, vf4* __restrict__ o4, int n4) {
  const int stride = gridDim.x * 256;
  for (int i = blockIdx.x * 256 + threadIdx.x; i < n4; i += stride) {
    const int pair = i / 25;
    const int pos = (i - pair * 25) * 4;
    o4[i] = onehot4(lat[pair], pos);
  }
}

// ---- fallback (R0 structure) if d_ws is too small ----
__global__ __launch_bounds__(256) void latency_encode_fused(
    const float* __restrict__ x, const float* __restrict__ noise,
    float* __restrict__ out, int npairs) {
  __shared__ int lat_s[256];
  const int tid = threadIdx.x;
  const int pairBase = blockIdx.x * 256;
  const int p = pairBase + tid;
  int lat = 255;
  if (p < npairs) lat = pair_latency_f64(x[p], noise[p]);
  lat_s[tid] = lat;
  __syncthreads();
  vf4* o4 = (vf4*)(out + (size_t)pairBase * T);
#pragma unroll
  for (int k = 0; k < 25; ++k) {
    const int fi4 = tid + k * 256;
    const int pl = fi4 / 25;
    const int pos = (fi4 % 25) * 4;
    if (pairBase + pl < npairs) o4[fi4] = onehot4(lat_s[pl], pos);
  }
}

extern "C" void kernel_launch(void* const* d_in, const int* in_sizes, int n_in,
                              void* d_out, int out_size, void* d_ws, size_t ws_size,
                              hipStream_t stream) {
  const float* x = (const float*)d_in[0];
  const float* noise = (const float*)d_in[1];
  float* out = (float*)d_out;
  const int npairs = in_sizes[0];  // 1,048,576

  if (ws_size >= (size_t)npairs) {
    unsigned char* lat = (unsigned char*)d_ws;
    lat_kernel<<<1024, 256, 0, stream>>>(x, noise, lat, npairs);
    const int n4 = out_size / 4;  // 26,214,400
    if (n4 == K2_STRIDE * K2_ITERS) {
      onehot_stream_prefetch<<<K2_GRID, 256, 0, stream>>>(lat, (vf4*)out);
    } else {
      onehot_stream_kernel<<<K2_GRID, 256, 0, stream>>>(lat, (vf4*)out, n4);
    }
  } else {
    const int grid = (npairs + 255) / 256;
    latency_encode_fused<<<grid, 256, 0, stream>>>(x, noise, out, npairs);
  }
}

// Round 12
// 81.163 us; speedup vs baseline: 1.2953x; 1.2953x over previous
//
#include <hip/hip_runtime.h>

// LatencyEncoder R11 = R7 restored EXACTLY (measured best: 79.7us).
// Ledger: R0/R4 fused select-stream 85.0/85.4 | R5 LDS-blit 88.0 | R6
// persistent+pipelined 88.1 | R7 two-kernel grid-stride 79.7 (BEST) | R8
// occupancy-cut 97.4 | R9 cheap-K1 81.1 (null) | R10 load-batch 105.1.
// Every axis probed (stream content, nt cache policy, ramp, store order,
// occupancy, compute cost, load scheduling); all null-or-negative vs R7.
// 430 MB moved / 79.7us = 5.4-5.7 TB/s = ~85% of the in-situ fill reference
// (6.85 TB/s on 4x-longer dispatches) -> practical write-BW roofline for an
// 80us dispatch.
//
// K1: per-pair latency, f64 chain bit-matches numpy ref (absmax 0.0 in every
//     passing round) -> u8 table in d_ws (1 MB, L2-resident for K2).
// K2: grid-stride one-hot stream, 2048 blocks (32 waves/CU), simple loop:
//     dense sliding store window -> DRAM row locality (the R7 win, -6%).

#define T 100

typedef float vf4 __attribute__((ext_vector_type(4)));

__device__ __forceinline__ int pair_latency_f64(float xv, float nv) {
  double xn = (double)xv + (double)nv * 0.01;
  double s = 1.0 / (1.0 + exp(-xn));
  int li = (int)rint((1.0 - s) * 99.0);
  li = li < 0 ? 0 : (li > 99 ? 99 : li);
  return (s > 0.5) ? li : 255;  // 255: no spike
}

__global__ __launch_bounds__(256) void lat_kernel(
    const float* __restrict__ x, const float* __restrict__ noise,
    unsigned char* __restrict__ lat, int npairs) {
  const int stride = gridDim.x * 256;
  for (int p = blockIdx.x * 256 + threadIdx.x; p < npairs; p += stride)
    lat[p] = (unsigned char)pair_latency_f64(x[p], noise[p]);
}

__global__ __launch_bounds__(256) void onehot_stream_kernel(
    const unsigned char* __restrict__ lat, vf4* __restrict__ o4, int n4) {
  const int stride = gridDim.x * 256;
  for (int i = blockIdx.x * 256 + threadIdx.x; i < n4; i += stride) {
    const int pair = i / 25;              // magic-mul div
    const int pos = (i - pair * 25) * 4;  // element offset within pair
    const int L = lat[pair];              // u8, L1-hit broadcast (~3/wave)
    vf4 v;
    v.x = (L == pos + 0) ? 1.0f : 0.0f;
    v.y = (L == pos + 1) ? 1.0f : 0.0f;
    v.z = (L == pos + 2) ? 1.0f : 0.0f;
    v.w = (L == pos + 3) ? 1.0f : 0.0f;
    o4[i] = v;
  }
}

// ---- fallback (R0 structure) if d_ws is too small ----
__global__ __launch_bounds__(256) void latency_encode_fused(
    const float* __restrict__ x, const float* __restrict__ noise,
    float* __restrict__ out, int npairs) {
  __shared__ int lat_s[256];
  const int tid = threadIdx.x;
  const int pairBase = blockIdx.x * 256;
  const int p = pairBase + tid;
  int lat = 255;
  if (p < npairs) lat = pair_latency_f64(x[p], noise[p]);
  lat_s[tid] = lat;
  __syncthreads();
  vf4* o4 = (vf4*)(out + (size_t)pairBase * T);
#pragma unroll
  for (int k = 0; k < 25; ++k) {
    const int fi4 = tid + k * 256;
    const int pl = fi4 / 25;
    const int pos = (fi4 % 25) * 4;
    const int L = lat_s[pl];
    vf4 v;
    v.x = (L == pos + 0) ? 1.0f : 0.0f;
    v.y = (L == pos + 1) ? 1.0f : 0.0f;
    v.z = (L == pos + 2) ? 1.0f : 0.0f;
    v.w = (L == pos + 3) ? 1.0f : 0.0f;
    if (pairBase + pl < npairs) o4[fi4] = v;
  }
}

extern "C" void kernel_launch(void* const* d_in, const int* in_sizes, int n_in,
                              void* d_out, int out_size, void* d_ws, size_t ws_size,
                              hipStream_t stream) {
  const float* x = (const float*)d_in[0];
  const float* noise = (const float*)d_in[1];
  float* out = (float*)d_out;
  const int npairs = in_sizes[0];  // 1,048,576

  if (ws_size >= (size_t)npairs) {
    unsigned char* lat = (unsigned char*)d_ws;
    lat_kernel<<<1024, 256, 0, stream>>>(x, noise, lat, npairs);
    const int n4 = out_size / 4;  // 26,214,400
    onehot_stream_kernel<<<2048, 256, 0, stream>>>(lat, (vf4*)out, n4);
  } else {
    const int grid = (npairs + 255) / 256;
    latency_encode_fused<<<grid, 256, 0, stream>>>(x, noise, out, npairs);
  }
}